// Round 7
// baseline (196.336 us; speedup 1.0000x reference)
//
#include <hip/hip_runtime.h>

// Problem constants (reference: N=16384, K=32, D=256)
#define N_ 16384
#define K_ 32
#define D_ 256
#define NEG_SLOPE 0.01f

#define GRID_ 1024   // exactly 4 resident blocks x 256 CUs
#define ITER_ 16     // consecutive n per block; GRID_*ITER_ == N_

// ---------------------------------------------------------------------------
// Prologue: ONE dispatch, one block, no atomics.
//   ws[0..255] = v = a_w @ W ; ws[256] = 2*dot(b,a_w) + a_b
// ---------------------------------------------------------------------------
__global__ __launch_bounds__(1024) void prep_kernel(
    const float* __restrict__ W, const float* __restrict__ b,
    const float* __restrict__ a_w, const float* __restrict__ a_b,
    float* __restrict__ ws) {
  __shared__ float part[4][D_];
  __shared__ float sp[4];
  const int t = threadIdx.x;
  const int dd = t >> 8;   // 0..3
  const int e = t & 255;
  float acc = 0.f;
#pragma unroll 8
  for (int j = 0; j < 64; ++j) {
    const int d = dd * 64 + j;
    acc += a_w[d] * W[d * D_ + e];   // coalesced over e
  }
  part[dd][e] = acc;
  if (t < D_) {
    float s = b[t] * a_w[t];
#pragma unroll
    for (int off = 1; off < 64; off <<= 1) s += __shfl_xor(s, off);
    if ((t & 63) == 0) sp[t >> 6] = s;
  }
  __syncthreads();
  if (t < D_) ws[t] = part[0][t] + part[1][t] + part[2][t] + part[3][t];
  if (t == 0) ws[D_] = 2.f * (sp[0] + sp[1] + sp[2] + sp[3]) + a_b[0];
}

// ---------------------------------------------------------------------------
// Main: persistent 512-thread blocks, ITER_ n's each, register double-buffer.
// Raw s_barrier with lgkmcnt-only drain => next-n global loads (into regs)
// stay in flight across both barriers; compiler emits exact vmcnt(5) before
// the current buffer's consumers. Wave kg owns k-rows 4kg..4kg+3; lane l
// owns columns 4l..4l+3 (m[4] = 16 VGPR per buffer).
// ---------------------------------------------------------------------------
struct MBuf {
  float4 m[4];
  float tg;
};

__device__ __forceinline__ void issue_loads(
    MBuf& bf, const float* __restrict__ middle,
    const float* __restrict__ target, int n, int kg, int l, int t) {
  const float4* m4p = (const float4*)(middle + (size_t)n * K_ * D_);
#pragma unroll
  for (int j = 0; j < 4; ++j) bf.m[j] = m4p[(kg * 4 + j) * 64 + l];
  // all 512 threads load (upper waves duplicate lower's cacheline - L2 hit)
  bf.tg = target[(size_t)n * D_ + (t & 255)];
}

__device__ __forceinline__ void lgk_barrier() {
  asm volatile("s_waitcnt lgkmcnt(0)" ::: "memory");
  __builtin_amdgcn_s_barrier();
}

__device__ __forceinline__ void process(
    const MBuf& bf, float (*part)[D_], float* sdot, float* stp,
    const float4& vv, float vt, float cadd,
    float* __restrict__ outrow, int t, int kg, int l) {
  // pass 1: partial dots + value-halving butterfly (10 shuffles)
  float pd[4];
#pragma unroll
  for (int j = 0; j < 4; ++j)
    pd[j] = bf.m[j].x * vv.x + bf.m[j].y * vv.y + bf.m[j].z * vv.z +
            bf.m[j].w * vv.w;
#pragma unroll
  for (int j = 0; j < 4; ++j) pd[j] += __shfl_xor(pd[j], 32);
  float q0 = (l & 32) ? pd[2] : pd[0];
  float q1 = (l & 32) ? pd[3] : pd[1];
  q0 += __shfl_xor(q0, 16);
  q1 += __shfl_xor(q1, 16);
  float r = (l & 16) ? q1 : q0;
  r += __shfl_xor(r, 8);
  r += __shfl_xor(r, 4);
  r += __shfl_xor(r, 2);
  r += __shfl_xor(r, 1);
  if ((l & 15) == 0)
    sdot[kg * 4 + ((l >> 5) * 2 + ((l >> 4) & 1))] = r;

  // target[n] . v (waves 0..3 hold the 256 real target lanes)
  if (t < D_) {
    float tp = bf.tg * vt;
#pragma unroll
    for (int off = 1; off < 64; off <<= 1) tp += __shfl_xor(tp, off);
    if (l == 0) stp[kg] = tp;
  }
  lgk_barrier();  // sdot, stp visible; B-loads remain in flight

  // softmax over K=32, redundantly in every wave
  const float tdot = stp[0] + stp[1] + stp[2] + stp[3];
  float sc = sdot[l & 31] + tdot + cadd;
  sc = sc > 0.f ? sc : NEG_SLOPE * sc;  // leaky_relu
  float mx = sc;
  mx = fmaxf(mx, __shfl_xor(mx, 1));
  mx = fmaxf(mx, __shfl_xor(mx, 2));
  mx = fmaxf(mx, __shfl_xor(mx, 4));
  mx = fmaxf(mx, __shfl_xor(mx, 8));
  mx = fmaxf(mx, __shfl_xor(mx, 16));
  const float ex = __expf(sc - mx);
  float sm = ex;
  sm += __shfl_xor(sm, 1);
  sm += __shfl_xor(sm, 2);
  sm += __shfl_xor(sm, 4);
  sm += __shfl_xor(sm, 8);
  sm += __shfl_xor(sm, 16);
  const float coef = ex / sm;  // lane l: coef[k = l&31]

  // pass 2: registers only; coef broadcast via uniform readlane
  float4 acc = make_float4(0.f, 0.f, 0.f, 0.f);
#pragma unroll
  for (int j = 0; j < 4; ++j) {
    const float cf = __int_as_float(
        __builtin_amdgcn_readlane(__float_as_int(coef), kg * 4 + j));
    acc.x += cf * bf.m[j].x;
    acc.y += cf * bf.m[j].y;
    acc.z += cf * bf.m[j].z;
    acc.w += cf * bf.m[j].w;
  }
  *(float4*)(&part[kg][4 * l]) = acc;
  lgk_barrier();  // part visible; B-loads still in flight

  // final: wave 0 sums 8 wave-partials, single 1KB coalesced store
  if (t < 64) {
    float4 o = make_float4(0.f, 0.f, 0.f, 0.f);
#pragma unroll
    for (int w = 0; w < 8; ++w) {
      const float4 p = *(const float4*)(&part[w][4 * t]);
      o.x += p.x; o.y += p.y; o.z += p.z; o.w += p.w;
    }
    ((float4*)outrow)[t] = o;
  }
}

__global__ __launch_bounds__(512, 8) void attn_agg_kernel(
    const float* __restrict__ target, const float* __restrict__ middle,
    const float* __restrict__ ws, float* __restrict__ out) {
  __shared__ __align__(16) float part[8][D_];  // 8 KB
  __shared__ float sdot[K_];
  __shared__ float stp[4];

  const int t = threadIdx.x;
  const int kg = t >> 6;
  const int l = t & 63;
  const int n0 = blockIdx.x * ITER_;

  const float4 vv = ((const float4*)ws)[l];   // v[4l..4l+3]
  const float vt = ws[t & 255];               // v[t] for tdot lanes
  const float cadd = ws[D_];

  MBuf A, B;
  issue_loads(A, middle, target, n0, kg, l, t);

#pragma unroll 1
  for (int it = 0; it < ITER_; it += 2) {
    issue_loads(B, middle, target, n0 + it + 1, kg, l, t);
    process(A, part, sdot, stp, vv, vt, cadd,
            out + (size_t)(n0 + it) * D_, t, kg, l);
    if (it + 2 < ITER_)
      issue_loads(A, middle, target, n0 + it + 2, kg, l, t);
    process(B, part, sdot, stp, vv, vt, cadd,
            out + (size_t)(n0 + it + 1) * D_, t, kg, l);
  }
}

extern "C" void kernel_launch(void* const* d_in, const int* in_sizes, int n_in,
                              void* d_out, int out_size, void* d_ws, size_t ws_size,
                              hipStream_t stream) {
  const float* target = (const float*)d_in[0];
  const float* middle = (const float*)d_in[1];
  const float* W      = (const float*)d_in[2];
  const float* b      = (const float*)d_in[3];
  const float* a_w    = (const float*)d_in[4];
  const float* a_b    = (const float*)d_in[5];
  float* out = (float*)d_out;
  float* ws  = (float*)d_ws;  // needs (D_+1) floats

  prep_kernel<<<1, 1024, 0, stream>>>(W, b, a_w, a_b, ws);
  attn_agg_kernel<<<GRID_, 512, 0, stream>>>(target, middle, ws, out);
}

// Round 8
// 122.577 us; speedup vs baseline: 1.6017x; 1.6017x over previous
//
#include <hip/hip_runtime.h>

// Problem constants (reference: N=16384, K=32, D=256)
#define N_ 16384
#define K_ 32
#define D_ 256
#define NEG_SLOPE 0.01f

#define GRID_ 1024   // 4 blocks per CU over the run (2 resident at a time)
#define ITER_ 16     // consecutive n per block; GRID_*ITER_ == N_

// ---------------------------------------------------------------------------
// Prologue: ONE dispatch, one block, no atomics.
//   ws[0..255] = v = a_w @ W ; ws[256] = 2*dot(b,a_w) + a_b
// ---------------------------------------------------------------------------
__global__ __launch_bounds__(1024) void prep_kernel(
    const float* __restrict__ W, const float* __restrict__ b,
    const float* __restrict__ a_w, const float* __restrict__ a_b,
    float* __restrict__ ws) {
  __shared__ float part[4][D_];
  __shared__ float sp[4];
  const int t = threadIdx.x;
  const int dd = t >> 8;   // 0..3
  const int e = t & 255;
  float acc = 0.f;
#pragma unroll 8
  for (int j = 0; j < 64; ++j) {
    const int d = dd * 64 + j;
    acc += a_w[d] * W[d * D_ + e];   // coalesced over e
  }
  part[dd][e] = acc;
  if (t < D_) {
    float s = b[t] * a_w[t];
#pragma unroll
    for (int off = 1; off < 64; off <<= 1) s += __shfl_xor(s, off);
    if ((t & 63) == 0) sp[t >> 6] = s;
  }
  __syncthreads();
  if (t < D_) ws[t] = part[0][t] + part[1][t] + part[2][t] + part[3][t];
  if (t == 0) ws[D_] = 2.f * (sp[0] + sp[1] + sp[2] + sp[3]) + a_b[0];
}

// ---------------------------------------------------------------------------
// Main: persistent 512-thread blocks, ITER_ n's each, register double-buffer.
// Raw s_barrier with lgkmcnt-only drain => next-n global loads (into regs)
// stay in flight across both barriers; compiler emits exact vmcnt(N) before
// the current buffer's consumers. __launch_bounds__(512,4): 128-VGPR budget
// so BOTH buffers (2 x 17 VGPR) + temps fit with NO spill (R6 failed at 64).
// ---------------------------------------------------------------------------
struct MBuf {
  float4 m[4];
  float tg;
};

__device__ __forceinline__ void issue_loads(
    MBuf& bf, const float* __restrict__ middle,
    const float* __restrict__ target, int n, int kg, int l, int t) {
  const float4* m4p = (const float4*)(middle + (size_t)n * K_ * D_);
#pragma unroll
  for (int j = 0; j < 4; ++j) bf.m[j] = m4p[(kg * 4 + j) * 64 + l];
  // all 512 threads load (upper waves duplicate lower's cacheline - L2 hit)
  bf.tg = target[(size_t)n * D_ + (t & 255)];
}

__device__ __forceinline__ void lgk_barrier() {
  asm volatile("s_waitcnt lgkmcnt(0)" ::: "memory");
  __builtin_amdgcn_s_barrier();
}

__device__ __forceinline__ void process(
    const MBuf& bf, float (*part)[D_], float* sdot, float* stp,
    const float4& vv, float vt, float cadd,
    float* __restrict__ outrow, int t, int kg, int l) {
  // pass 1: partial dots + value-halving butterfly (10 shuffles)
  float pd[4];
#pragma unroll
  for (int j = 0; j < 4; ++j)
    pd[j] = bf.m[j].x * vv.x + bf.m[j].y * vv.y + bf.m[j].z * vv.z +
            bf.m[j].w * vv.w;
#pragma unroll
  for (int j = 0; j < 4; ++j) pd[j] += __shfl_xor(pd[j], 32);
  float q0 = (l & 32) ? pd[2] : pd[0];
  float q1 = (l & 32) ? pd[3] : pd[1];
  q0 += __shfl_xor(q0, 16);
  q1 += __shfl_xor(q1, 16);
  float r = (l & 16) ? q1 : q0;
  r += __shfl_xor(r, 8);
  r += __shfl_xor(r, 4);
  r += __shfl_xor(r, 2);
  r += __shfl_xor(r, 1);
  if ((l & 15) == 0)
    sdot[kg * 4 + ((l >> 5) * 2 + ((l >> 4) & 1))] = r;

  // target[n] . v (waves 0..3 hold the 256 real target lanes)
  if (t < D_) {
    float tp = bf.tg * vt;
#pragma unroll
    for (int off = 1; off < 64; off <<= 1) tp += __shfl_xor(tp, off);
    if (l == 0) stp[kg] = tp;
  }
  lgk_barrier();  // sdot, stp visible; next-n loads remain in flight

  // softmax over K=32, redundantly in every wave
  const float tdot = stp[0] + stp[1] + stp[2] + stp[3];
  float sc = sdot[l & 31] + tdot + cadd;
  sc = sc > 0.f ? sc : NEG_SLOPE * sc;  // leaky_relu
  float mx = sc;
  mx = fmaxf(mx, __shfl_xor(mx, 1));
  mx = fmaxf(mx, __shfl_xor(mx, 2));
  mx = fmaxf(mx, __shfl_xor(mx, 4));
  mx = fmaxf(mx, __shfl_xor(mx, 8));
  mx = fmaxf(mx, __shfl_xor(mx, 16));
  const float ex = __expf(sc - mx);
  float sm = ex;
  sm += __shfl_xor(sm, 1);
  sm += __shfl_xor(sm, 2);
  sm += __shfl_xor(sm, 4);
  sm += __shfl_xor(sm, 8);
  sm += __shfl_xor(sm, 16);
  const float coef = ex / sm;  // lane l: coef[k = l&31]

  // pass 2: registers only; coef broadcast via uniform readlane
  float4 acc = make_float4(0.f, 0.f, 0.f, 0.f);
#pragma unroll
  for (int j = 0; j < 4; ++j) {
    const float cf = __int_as_float(
        __builtin_amdgcn_readlane(__float_as_int(coef), kg * 4 + j));
    acc.x += cf * bf.m[j].x;
    acc.y += cf * bf.m[j].y;
    acc.z += cf * bf.m[j].z;
    acc.w += cf * bf.m[j].w;
  }
  *(float4*)(&part[kg][4 * l]) = acc;
  lgk_barrier();  // part visible; next-n loads still in flight

  // final: wave 0 sums 8 wave-partials, single 1KB coalesced store
  if (t < 64) {
    float4 o = make_float4(0.f, 0.f, 0.f, 0.f);
#pragma unroll
    for (int w = 0; w < 8; ++w) {
      const float4 p = *(const float4*)(&part[w][4 * t]);
      o.x += p.x; o.y += p.y; o.z += p.z; o.w += p.w;
    }
    ((float4*)outrow)[t] = o;
  }
}

__global__ __launch_bounds__(512, 4) void attn_agg_kernel(
    const float* __restrict__ target, const float* __restrict__ middle,
    const float* __restrict__ ws, float* __restrict__ out) {
  __shared__ __align__(16) float part[8][D_];  // 8 KB
  __shared__ float sdot[K_];
  __shared__ float stp[4];

  const int t = threadIdx.x;
  const int kg = t >> 6;
  const int l = t & 63;
  const int n0 = blockIdx.x * ITER_;

  const float4 vv = ((const float4*)ws)[l];   // v[4l..4l+3]
  const float vt = ws[t & 255];               // v[t] for tdot lanes
  const float cadd = ws[D_];

  MBuf A, B;
  issue_loads(A, middle, target, n0, kg, l, t);

#pragma unroll 1
  for (int it = 0; it < ITER_; it += 2) {
    issue_loads(B, middle, target, n0 + it + 1, kg, l, t);
    process(A, part, sdot, stp, vv, vt, cadd,
            out + (size_t)(n0 + it) * D_, t, kg, l);
    if (it + 2 < ITER_)
      issue_loads(A, middle, target, n0 + it + 2, kg, l, t);
    process(B, part, sdot, stp, vv, vt, cadd,
            out + (size_t)(n0 + it + 1) * D_, t, kg, l);
  }
}

extern "C" void kernel_launch(void* const* d_in, const int* in_sizes, int n_in,
                              void* d_out, int out_size, void* d_ws, size_t ws_size,
                              hipStream_t stream) {
  const float* target = (const float*)d_in[0];
  const float* middle = (const float*)d_in[1];
  const float* W      = (const float*)d_in[2];
  const float* b      = (const float*)d_in[3];
  const float* a_w    = (const float*)d_in[4];
  const float* a_b    = (const float*)d_in[5];
  float* out = (float*)d_out;
  float* ws  = (float*)d_ws;  // needs (D_+1) floats

  prep_kernel<<<1, 1024, 0, stream>>>(W, b, a_w, a_b, ws);
  attn_agg_kernel<<<GRID_, 512, 0, stream>>>(target, middle, ws, out);
}

// Round 9
// 111.479 us; speedup vs baseline: 1.7612x; 1.0996x over previous
//
#include <hip/hip_runtime.h>

// Problem constants (reference: N=16384, K=32, D=256)
#define N_ 16384
#define K_ 32
#define D_ 256
#define NEG_SLOPE 0.01f

// ---------------------------------------------------------------------------
// Prologue (parallel): ws[0..255] = v = a_w @ W, ws[256] = 2*dot(b,a_w)+a_b.
// ws zeroed by hipMemsetAsync; 32 blocks accumulate via atomicAdd (distinct
// addresses, 32 adds each -> negligible contention).
// ---------------------------------------------------------------------------
__global__ __launch_bounds__(256) void prep_kernel(
    const float* __restrict__ W, const float* __restrict__ b,
    const float* __restrict__ a_w, const float* __restrict__ a_b,
    float* __restrict__ ws) {
  const int t = threadIdx.x;  // column e
  const int i = blockIdx.x;   // 0..31
  float acc = 0.f;
#pragma unroll
  for (int j = 0; j < 8; ++j) {
    const int d = i * 8 + j;
    acc += a_w[d] * W[d * D_ + t];
  }
  atomicAdd(&ws[t], acc);

  if (i == 0) {
    float s = b[t] * a_w[t];
#pragma unroll
    for (int off = 1; off < 64; off <<= 1) s += __shfl_xor(s, off);
    __shared__ float sp[4];
    if ((t & 63) == 0) sp[t >> 6] = s;
    __syncthreads();
    if (t == 0)
      atomicAdd(&ws[D_], 2.f * (sp[0] + sp[1] + sp[2] + sp[3]) + a_b[0]);
  }
}

// ---------------------------------------------------------------------------
// Main: one 512-thread block per n, COLUMN-SLICE layout, ONE barrier.
// Wave kg owns columns 32kg..32kg+31 for ALL K=32 rows:
//   lane l: rg = l>>3 selects row-within-group, c = l&7 selects 4 columns.
//   m[j] = middle[n][8j+rg][32kg+4c .. +3]  (4 float4 = 16 VGPR)
// pass 1: per-row partial dots, reduce over c (3 shfl/row-grp), write
//         sdot_part[kg][row] (1 KB LDS)  | barrier |
// softmax: every lane sums 8 wave-partials for its k=l&31, butterflies.
// pass 2: coef via 4 bpermutes, FMA on registers, reduce over rg
//         (12 shfl), wave stores its own 128 B of out. No part[] LDS,
//         no second barrier, no wave0-only tail.
// ---------------------------------------------------------------------------
__global__ __launch_bounds__(512, 8) void attn_agg_kernel(
    const float* __restrict__ target, const float* __restrict__ middle,
    const float* __restrict__ ws, float* __restrict__ out) {
  __shared__ float sdot_part[8][K_];  // [wave][k] partial dots, 1 KB
  __shared__ float stgt[8];           // [wave] partial of target.v

  const int t = threadIdx.x;
  const int kg = t >> 6;   // wave 0..7 -> columns 32kg..32kg+31
  const int l = t & 63;
  const int rg = l >> 3;   // 0..7: row-in-group
  const int c = l & 7;     // 0..7: 4-column sub-slice
  const int n = blockIdx.x;

  const float* mbase = middle + (size_t)n * K_ * D_ + kg * 32 + c * 4;

  // Load all 32 rows of this wave's column slice: 4 instrs, each touching
  // 8 x 128B segments (rows 8j+0..7), full cache lines.
  float4 m[4];
#pragma unroll
  for (int j = 0; j < 4; ++j)
    m[j] = *(const float4*)(mbase + (size_t)(8 * j + rg) * D_);

  const float4 vv = *(const float4*)(ws + kg * 32 + c * 4);
  const float cadd = ws[D_];
  const float4 tg = *(const float4*)(target + (size_t)n * D_ + kg * 32 + c * 4);

  // pass 1: partial dot of row 8j+rg over this lane's 4 columns
  float pd[4];
#pragma unroll
  for (int j = 0; j < 4; ++j)
    pd[j] = m[j].x * vv.x + m[j].y * vv.y + m[j].z * vv.z + m[j].w * vv.w;
  // reduce over the 8-lane c-octet (same row, neighboring columns)
#pragma unroll
  for (int j = 0; j < 4; ++j) {
    pd[j] += __shfl_xor(pd[j], 1);
    pd[j] += __shfl_xor(pd[j], 2);
    pd[j] += __shfl_xor(pd[j], 4);
  }
  if (c == 0) {
#pragma unroll
    for (int j = 0; j < 4; ++j) sdot_part[kg][8 * j + rg] = pd[j];
  }

  // target[n].v partial over this wave's 32 columns (rg-duplicated, harmless)
  float tp = tg.x * vv.x + tg.y * vv.y + tg.z * vv.z + tg.w * vv.w;
  tp += __shfl_xor(tp, 1);
  tp += __shfl_xor(tp, 2);
  tp += __shfl_xor(tp, 4);
  if (l == 0) stgt[kg] = tp;

  __syncthreads();  // sdot_part, stgt visible (only barrier in the kernel)

  // score for k = l&31 (both half-waves duplicate)
  const int k2 = l & 31;
  float sd = cadd;
#pragma unroll
  for (int w = 0; w < 8; ++w) sd += sdot_part[w][k2];  // distinct banks
#pragma unroll
  for (int w = 0; w < 8; ++w) sd += stgt[w];           // broadcast reads

  float sc = sd > 0.f ? sd : NEG_SLOPE * sd;  // leaky_relu
  float mx = sc;
  mx = fmaxf(mx, __shfl_xor(mx, 1));
  mx = fmaxf(mx, __shfl_xor(mx, 2));
  mx = fmaxf(mx, __shfl_xor(mx, 4));
  mx = fmaxf(mx, __shfl_xor(mx, 8));
  mx = fmaxf(mx, __shfl_xor(mx, 16));
  const float ex = __expf(sc - mx);
  float sm = ex;
  sm += __shfl_xor(sm, 1);
  sm += __shfl_xor(sm, 2);
  sm += __shfl_xor(sm, 4);
  sm += __shfl_xor(sm, 8);
  sm += __shfl_xor(sm, 16);
  const float coef = ex / sm;  // lane l holds coef[k = l&31]

  // pass 2: fetch this lane's 4 row-coefs (rows 8j+rg, all in lanes 0..31)
  float4 acc = make_float4(0.f, 0.f, 0.f, 0.f);
#pragma unroll
  for (int j = 0; j < 4; ++j) {
    const float cf = __shfl(coef, 8 * j + rg, 64);
    acc.x += cf * m[j].x;
    acc.y += cf * m[j].y;
    acc.z += cf * m[j].z;
    acc.w += cf * m[j].w;
  }
  // reduce over rg (lanes with same c, different rg): xor 8,16,32
#pragma unroll
  for (int off = 8; off <= 32; off <<= 1) {
    acc.x += __shfl_xor(acc.x, off);
    acc.y += __shfl_xor(acc.y, off);
    acc.z += __shfl_xor(acc.z, off);
    acc.w += __shfl_xor(acc.w, off);
  }
  if (rg == 0)  // 8 lanes store 128 B contiguous: out[n][32kg+4c .. +3]
    *(float4*)(out + (size_t)n * D_ + kg * 32 + c * 4) = acc;
}

extern "C" void kernel_launch(void* const* d_in, const int* in_sizes, int n_in,
                              void* d_out, int out_size, void* d_ws, size_t ws_size,
                              hipStream_t stream) {
  const float* target = (const float*)d_in[0];
  const float* middle = (const float*)d_in[1];
  const float* W      = (const float*)d_in[2];
  const float* b      = (const float*)d_in[3];
  const float* a_w    = (const float*)d_in[4];
  const float* a_b    = (const float*)d_in[5];
  float* out = (float*)d_out;
  float* ws  = (float*)d_ws;  // needs (D_+1) floats

  hipMemsetAsync(ws, 0, (D_ + 1) * sizeof(float), stream);
  prep_kernel<<<32, 256, 0, stream>>>(W, b, a_w, a_b, ws);
  attn_agg_kernel<<<N_, 512, 0, stream>>>(target, middle, ws, out);
}

// Round 10
// 108.420 us; speedup vs baseline: 1.8109x; 1.0282x over previous
//
#include <hip/hip_runtime.h>

// Problem constants (reference: N=16384, K=32, D=256)
#define N_ 16384
#define K_ 32
#define D_ 256
#define NEG_SLOPE 0.01f

// ---------------------------------------------------------------------------
// Prologue: ONE dispatch, one block, no atomics (no memset needed).
//   ws[0..255] = v = a_w @ W ; ws[256] = 2*dot(b,a_w) + a_b
// Algebraic collapse: score[n,k] = (target[n]+middle[n,k]).v + c with
// v = a_w @ W, c = 2*dot(b,a_w) + a_b  -- the O(N*K*D^2) matmuls vanish.
// ---------------------------------------------------------------------------
__global__ __launch_bounds__(1024) void prep_kernel(
    const float* __restrict__ W, const float* __restrict__ b,
    const float* __restrict__ a_w, const float* __restrict__ a_b,
    float* __restrict__ ws) {
  __shared__ float part[4][D_];
  __shared__ float sp[4];
  const int t = threadIdx.x;
  const int dd = t >> 8;   // 0..3
  const int e = t & 255;
  float acc = 0.f;
#pragma unroll 8
  for (int j = 0; j < 64; ++j) {
    const int d = dd * 64 + j;
    acc += a_w[d] * W[d * D_ + e];   // coalesced over e
  }
  part[dd][e] = acc;

  // scalar bias term: reduce b[t]*a_w[t] over t<256 (waves 0..3)
  if (t < D_) {
    float s = b[t] * a_w[t];
#pragma unroll
    for (int off = 1; off < 64; off <<= 1) s += __shfl_xor(s, off);
    if ((t & 63) == 0) sp[t >> 6] = s;
  }
  __syncthreads();
  if (t < D_) ws[t] = part[0][t] + part[1][t] + part[2][t] + part[3][t];
  if (t == 0) ws[D_] = 2.f * (sp[0] + sp[1] + sp[2] + sp[3]) + a_b[0];
}

// ---------------------------------------------------------------------------
// Main (best measured structure, R5 = 108.4 us): one 512-thread block per n.
// Wave kg owns k-rows 4kg..4kg+3 (contiguous 1KB row loads); lane l owns
// columns 4l..4l+3 (m[4] = 16 VGPR). Two barriers:
//   pass1 dots -> sdot (LDS) | barrier | softmax redundantly in ALL 8 waves
//   (coef via uniform readlane -> SALU broadcast) -> pass2 on registers ->
//   part (LDS) | barrier | wave0 float4 column-sum + 1KB coalesced store.
// <=64 VGPR -> 4 blocks/CU; many independent blocks = the latency hiding
// that beat every explicit pipelining attempt (R1/R6/R7) and the 1-barrier
// scattered-load layout (R8).
// ---------------------------------------------------------------------------
__global__ __launch_bounds__(512, 8) void attn_agg_kernel(
    const float* __restrict__ target, const float* __restrict__ middle,
    const float* __restrict__ ws, float* __restrict__ out) {
  __shared__ __align__(16) float part[8][D_];  // 8 KB
  __shared__ float sdot[K_];
  __shared__ float stp[4];

  const int t = threadIdx.x;
  const int kg = t >> 6;   // wave 0..7, owns k = 4kg..4kg+3
  const int l = t & 63;
  const int n = blockIdx.x;

  const float4* m4p = (const float4*)(middle + (size_t)n * K_ * D_);
  float4 m[4];
#pragma unroll
  for (int j = 0; j < 4; ++j) m[j] = m4p[(kg * 4 + j) * 64 + l];

  const float4 vv = ((const float4*)ws)[l];  // v[4l..4l+3]
  const float cadd = ws[D_];

  // pass 1: partial dots + value-halving butterfly (10 shuffles)
  float pd[4];
#pragma unroll
  for (int j = 0; j < 4; ++j)
    pd[j] = m[j].x * vv.x + m[j].y * vv.y + m[j].z * vv.z + m[j].w * vv.w;
#pragma unroll
  for (int j = 0; j < 4; ++j) pd[j] += __shfl_xor(pd[j], 32);
  float q0 = (l & 32) ? pd[2] : pd[0];
  float q1 = (l & 32) ? pd[3] : pd[1];
  q0 += __shfl_xor(q0, 16);
  q1 += __shfl_xor(q1, 16);
  float r = (l & 16) ? q1 : q0;
  r += __shfl_xor(r, 8);
  r += __shfl_xor(r, 4);
  r += __shfl_xor(r, 2);
  r += __shfl_xor(r, 1);
  if ((l & 15) == 0)
    sdot[kg * 4 + ((l >> 5) * 2 + ((l >> 4) & 1))] = r;

  // target[n] . v (waves 0..3)
  if (t < D_) {
    float tp = target[(size_t)n * D_ + t] * ws[t];
#pragma unroll
    for (int off = 1; off < 64; off <<= 1) tp += __shfl_xor(tp, off);
    if (l == 0) stp[kg] = tp;
  }
  __syncthreads();  // sdot, stp ready

  // softmax over K=32, redundantly in every wave (halves duplicate k=l&31)
  const float tdot = stp[0] + stp[1] + stp[2] + stp[3];
  float sc = sdot[l & 31] + tdot + cadd;
  sc = sc > 0.f ? sc : NEG_SLOPE * sc;  // leaky_relu
  float mx = sc;
  mx = fmaxf(mx, __shfl_xor(mx, 1));
  mx = fmaxf(mx, __shfl_xor(mx, 2));
  mx = fmaxf(mx, __shfl_xor(mx, 4));
  mx = fmaxf(mx, __shfl_xor(mx, 8));
  mx = fmaxf(mx, __shfl_xor(mx, 16));
  const float ex = __expf(sc - mx);
  float sm = ex;
  sm += __shfl_xor(sm, 1);
  sm += __shfl_xor(sm, 2);
  sm += __shfl_xor(sm, 4);
  sm += __shfl_xor(sm, 8);
  sm += __shfl_xor(sm, 16);
  const float coef = ex / sm;  // lane l holds coef[k = l&31] (both halves)

  // pass 2: registers only; coef broadcast via uniform readlane
  float4 acc = make_float4(0.f, 0.f, 0.f, 0.f);
#pragma unroll
  for (int j = 0; j < 4; ++j) {
    const float cf = __int_as_float(
        __builtin_amdgcn_readlane(__float_as_int(coef), kg * 4 + j));
    acc.x += cf * m[j].x;
    acc.y += cf * m[j].y;
    acc.z += cf * m[j].z;
    acc.w += cf * m[j].w;
  }
  *(float4*)(&part[kg][4 * l]) = acc;
  __syncthreads();  // part ready

  // final: wave 0 sums 8 wave-partials, float4, single 1KB coalesced store
  if (t < 64) {
    float4 o = make_float4(0.f, 0.f, 0.f, 0.f);
#pragma unroll
    for (int w = 0; w < 8; ++w) {
      const float4 p = *(const float4*)(&part[w][4 * t]);
      o.x += p.x; o.y += p.y; o.z += p.z; o.w += p.w;
    }
    ((float4*)(out + (size_t)n * D_))[t] = o;
  }
}

extern "C" void kernel_launch(void* const* d_in, const int* in_sizes, int n_in,
                              void* d_out, int out_size, void* d_ws, size_t ws_size,
                              hipStream_t stream) {
  const float* target = (const float*)d_in[0];
  const float* middle = (const float*)d_in[1];
  const float* W      = (const float*)d_in[2];
  const float* b      = (const float*)d_in[3];
  const float* a_w    = (const float*)d_in[4];
  const float* a_b    = (const float*)d_in[5];
  float* out = (float*)d_out;
  float* ws  = (float*)d_ws;  // needs (D_+1) floats

  prep_kernel<<<1, 1024, 0, stream>>>(W, b, a_w, a_b, ws);
  attn_agg_kernel<<<N_, 512, 0, stream>>>(target, middle, ws, out);
}